// Round 8
// baseline (71686.041 us; speedup 1.0000x reference)
//
#include <hip/hip_runtime.h>
#include <hip/hip_bf16.h>

// xLSTMStack: proj -> 4x( LN -> conv-mix -> bf16 MFMA GEMM (xg) -> cooperative GRU scan + residual )
// GRU v8: barrier-free register-flow ring. 256 WGs (b,s) x 512 thr; thread
// (w,g16,l16): dim jj=4w+g16, k-slice [32*l16,+32). Per step each thread polls
// its 16 u64 slots (tag32 | 2xbf16) with a per-slot done-mask straight into
// registers (no LDS staging, no __syncthreads in the loop; tag match IS the
// sync; depth-2 parity ring is overrun-safe by the poll dependency). Weights
// bf16-pair-packed in LDS [12][512] uint4 (conflict-free, aligned); 12
// ds_read_b128/step issued before the poll so they complete under the spin.
// Workspace (~134.1 MiB):
//   [0,96M)    xg bf16 [B*L*3H] (first 64 MiB aliased as ln fp32)
//   [96,128M)  mixbf bf16 [B*L*H]
//   [128,134M) wihbf bf16 [4*3H*H]
//   [134M,+64K) hst u64 [2][16][256]
// d_out (fp32 [B,L,H]) doubles as the inter-layer h buffer.

#define B_   16
#define L_   2048
#define IN_  64
#define H_   512
#define H3_  1536
#define NL_  4

typedef unsigned short u16;
typedef unsigned long long u64;
typedef short bf16x8 __attribute__((ext_vector_type(8)));
typedef float f32x4 __attribute__((ext_vector_type(4)));
typedef unsigned u32x4 __attribute__((ext_vector_type(4)));

__device__ __forceinline__ u16 f2bf(float f) {
  unsigned u = __float_as_uint(f);
  u = u + 0x7fffu + ((u >> 16) & 1u);
  return (u16)(u >> 16);
}
__device__ __forceinline__ float bf2f(u16 v) {
  return __uint_as_float(((unsigned)v) << 16);
}
__device__ __forceinline__ float gelu_exact(float x) {
  return 0.5f * x * (1.f + erff(x * 0.70710678118654752440f));
}
__device__ __forceinline__ float fast_sig(float x) {
  float e = __expf(-x);
  return __builtin_amdgcn_rcpf(1.f + e);
}
__device__ __forceinline__ float fast_tanh(float x) {
  x = fminf(fmaxf(x, -15.f), 15.f);
  float e = __expf(2.f * x);
  return (e - 1.f) * __builtin_amdgcn_rcpf(e + 1.f);
}

// ---------------- init: zero tagged h-state ----------------
__global__ void k_init(u64* hst, int n) {
  int i = blockIdx.x * blockDim.x + threadIdx.x;
  if (i < n) hst[i] = 0ull;
}

// ---------------- fp32 -> bf16 convert ----------------
__global__ void k_cvt(const float* __restrict__ in, u16* __restrict__ out, int n) {
  int i = blockIdx.x * blockDim.x + threadIdx.x;
  int stride = gridDim.x * blockDim.x;
  for (; i < n; i += stride) out[i] = f2bf(in[i]);
}

// ---------------- input projection: h = x @ Wp.T + bp ----------------
__global__ __launch_bounds__(512)
void k_proj(const float* __restrict__ x, const float* __restrict__ Wp,
            const float* __restrict__ bp, float* __restrict__ hb) {
  __shared__ float4 xs[128];
  const int tid = threadIdx.x;
  const size_t m0 = (size_t)blockIdx.x * 8;
  if (tid < 128) xs[tid] = ((const float4*)(x + m0 * IN_))[tid];
  __syncthreads();
  float4 wv[16];
  const float4* wp4 = (const float4*)(Wp + (size_t)tid * IN_);
#pragma unroll
  for (int i = 0; i < 16; ++i) wv[i] = wp4[i];
  float acc[8] = {0.f,0.f,0.f,0.f,0.f,0.f,0.f,0.f};
#pragma unroll
  for (int k = 0; k < 16; ++k) {
    float4 w4 = wv[k];
#pragma unroll
    for (int rr = 0; rr < 8; ++rr) {
      float4 xv = xs[rr * 16 + k];
      acc[rr] += w4.x * xv.x + w4.y * xv.y + w4.z * xv.z + w4.w * xv.w;
    }
  }
  float bpv = bp[tid];
#pragma unroll
  for (int rr = 0; rr < 8; ++rr) hb[(m0 + rr) * H_ + tid] = acc[rr] + bpv;
}

// ---------------- LayerNorm (one wave per row) ----------------
__global__ __launch_bounds__(256)
void k_ln(const float* __restrict__ hin, const float* __restrict__ g,
          const float* __restrict__ bta, float* __restrict__ lnout) {
  const int w = threadIdx.x >> 6, lane = threadIdx.x & 63;
  const size_t m = (size_t)blockIdx.x * 4 + w;
  const float4* src = (const float4*)(hin + m * H_);
  float4 a = src[lane * 2], c = src[lane * 2 + 1];
  float sm = a.x + a.y + a.z + a.w + c.x + c.y + c.z + c.w;
  float sq = a.x*a.x + a.y*a.y + a.z*a.z + a.w*a.w + c.x*c.x + c.y*c.y + c.z*c.z + c.w*c.w;
  sm += __shfl_xor(sm, 1);  sq += __shfl_xor(sq, 1);
  sm += __shfl_xor(sm, 2);  sq += __shfl_xor(sq, 2);
  sm += __shfl_xor(sm, 4);  sq += __shfl_xor(sq, 4);
  sm += __shfl_xor(sm, 8);  sq += __shfl_xor(sq, 8);
  sm += __shfl_xor(sm, 16); sq += __shfl_xor(sq, 16);
  sm += __shfl_xor(sm, 32); sq += __shfl_xor(sq, 32);
  float mu = sm * (1.f / 512.f);
  float var = sq * (1.f / 512.f) - mu * mu;
  float inv = 1.f / sqrtf(var + 1e-5f);
  const float4* g4 = (const float4*)g;
  const float4* b4 = (const float4*)bta;
  float4 ga = g4[lane * 2], gc = g4[lane * 2 + 1];
  float4 ba = b4[lane * 2], bc = b4[lane * 2 + 1];
  float4 oa, oc;
  oa.x = (a.x - mu) * inv * ga.x + ba.x;
  oa.y = (a.y - mu) * inv * ga.y + ba.y;
  oa.z = (a.z - mu) * inv * ga.z + ba.z;
  oa.w = (a.w - mu) * inv * ga.w + ba.w;
  oc.x = (c.x - mu) * inv * gc.x + bc.x;
  oc.y = (c.y - mu) * inv * gc.y + bc.y;
  oc.z = (c.z - mu) * inv * gc.z + bc.z;
  oc.w = (c.w - mu) * inv * gc.w + bc.w;
  float4* dst = (float4*)(lnout + m * H_);
  dst[lane * 2] = oa;
  dst[lane * 2 + 1] = oc;
}

// ---------------- fused conv(5,11,23)+BN+GELU+gate softmax+mix ----------------
__global__ __launch_bounds__(512)
void k_mix(const float* __restrict__ ln,
           const float* __restrict__ w0, const float* __restrict__ cb0,
           const float* __restrict__ w1, const float* __restrict__ cb1,
           const float* __restrict__ w2, const float* __restrict__ cb2,
           const float* __restrict__ bng, const float* __restrict__ bnb,
           const float* __restrict__ gW, const float* __restrict__ gb,
           u16* __restrict__ mixbf) {
  const int h = threadIdx.x;
  const int bi = blockIdx.x >> 11;
  const int t = blockIdx.x & (L_ - 1);
  const size_t mrow = (size_t)blockIdx.x;
  float v[23];
#pragma unroll
  for (int d = 0; d < 23; ++d) {
    int tt = t + d - 11;
    v[d] = (tt >= 0 && tt < L_) ? ln[((size_t)bi * L_ + tt) * H_ + h] : 0.f;
  }
  float o0 = cb0[h], o1 = cb1[h], o2 = cb2[h];
#pragma unroll
  for (int d = 0; d < 5; ++d) o0 += v[9 + d] * w0[h * 5 + d];
#pragma unroll
  for (int d = 0; d < 11; ++d) o1 += v[6 + d] * w1[h * 11 + d];
#pragma unroll
  for (int d = 0; d < 23; ++d) o2 += v[d] * w2[h * 23 + d];
  const float bscale = 0.99999500003749968f;  // 1/sqrt(1+1e-5)
  o0 = o0 * (bng[0 * H_ + h] * bscale) + bnb[0 * H_ + h];
  o1 = o1 * (bng[1 * H_ + h] * bscale) + bnb[1 * H_ + h];
  o2 = o2 * (bng[2 * H_ + h] * bscale) + bnb[2 * H_ + h];
  o0 = gelu_exact(o0); o1 = gelu_exact(o1); o2 = gelu_exact(o2);
  float l0 = o0 * gW[0 * H3_ + h] + o1 * gW[0 * H3_ + H_ + h] + o2 * gW[0 * H3_ + 2 * H_ + h];
  float l1 = o0 * gW[1 * H3_ + h] + o1 * gW[1 * H3_ + H_ + h] + o2 * gW[1 * H3_ + 2 * H_ + h];
  float l2 = o0 * gW[2 * H3_ + h] + o1 * gW[2 * H3_ + H_ + h] + o2 * gW[2 * H3_ + 2 * H_ + h];
  l0 += __shfl_xor(l0, 1);  l1 += __shfl_xor(l1, 1);  l2 += __shfl_xor(l2, 1);
  l0 += __shfl_xor(l0, 2);  l1 += __shfl_xor(l1, 2);  l2 += __shfl_xor(l2, 2);
  l0 += __shfl_xor(l0, 4);  l1 += __shfl_xor(l1, 4);  l2 += __shfl_xor(l2, 4);
  l0 += __shfl_xor(l0, 8);  l1 += __shfl_xor(l1, 8);  l2 += __shfl_xor(l2, 8);
  l0 += __shfl_xor(l0, 16); l1 += __shfl_xor(l1, 16); l2 += __shfl_xor(l2, 16);
  l0 += __shfl_xor(l0, 32); l1 += __shfl_xor(l1, 32); l2 += __shfl_xor(l2, 32);
  __shared__ float red[8][3];
  const int w = h >> 6, lane = h & 63;
  if (lane == 0) { red[w][0] = l0; red[w][1] = l1; red[w][2] = l2; }
  __syncthreads();
  l0 = gb[0]; l1 = gb[1]; l2 = gb[2];
#pragma unroll
  for (int i = 0; i < 8; ++i) { l0 += red[i][0]; l1 += red[i][1]; l2 += red[i][2]; }
  float mx = fmaxf(l0, fmaxf(l1, l2));
  float e0 = expf(l0 - mx), e1 = expf(l1 - mx), e2 = expf(l2 - mx);
  float inv = 1.f / (e0 + e1 + e2);
  float out = (o0 * e0 + o1 * e1 + o2 * e2) * inv;
  mixbf[mrow * H_ + h] = f2bf(out);
}

// ---------------- bf16 MFMA GEMM: xg = mixbf @ WihT + bih ----------------
__global__ __launch_bounds__(256)
void k_gemm(const u16* __restrict__ A, const u16* __restrict__ Bm,
            const float* __restrict__ bias, u16* __restrict__ C) {
  __shared__ u16 As[128 * 32];
  __shared__ u16 Bs[128 * 32];
  const int tid = threadIdx.x;
  const int bm = blockIdx.x / 12, bn = blockIdx.x % 12;
  const int m0 = bm * 128, n0 = bn * 128;
  const int w = tid >> 6, lane = tid & 63;
  const int wr = w >> 1, wc = w & 1;
  const int q = lane >> 4, r = lane & 15;
  f32x4 acc[4][4] = {};
  const uint4* Ag = (const uint4*)(A + (size_t)m0 * H_);
  const uint4* Bg = (const uint4*)(Bm + (size_t)n0 * H_);
  uint4* As4 = (uint4*)As;
  uint4* Bs4 = (uint4*)Bs;
  for (int ko = 0; ko < 16; ++ko) {
    __syncthreads();
#pragma unroll
    for (int i = 0; i < 2; ++i) {
      int j = tid + 256 * i;
      As4[j] = Ag[(size_t)(j >> 2) * 64 + (j & 3) + ko * 4];
      Bs4[j] = Bg[(size_t)(j >> 2) * 64 + (j & 3) + ko * 4];
    }
    __syncthreads();
    bf16x8 av[4], bv[4];
#pragma unroll
    for (int m = 0; m < 4; ++m) av[m] = *(const bf16x8*)&As[(wr * 64 + m * 16 + r) * 32 + q * 8];
#pragma unroll
    for (int n = 0; n < 4; ++n) bv[n] = *(const bf16x8*)&Bs[(wc * 64 + n * 16 + r) * 32 + q * 8];
#pragma unroll
    for (int m = 0; m < 4; ++m)
#pragma unroll
      for (int n = 0; n < 4; ++n)
        acc[m][n] = __builtin_amdgcn_mfma_f32_16x16x32_bf16(av[m], bv[n], acc[m][n], 0, 0, 0);
  }
#pragma unroll
  for (int n = 0; n < 4; ++n) {
    int col = n0 + wc * 64 + n * 16 + r;
    float bv_ = bias[col];
#pragma unroll
    for (int m = 0; m < 4; ++m) {
      int row = m0 + wr * 64 + m * 16 + q * 4;
#pragma unroll
      for (int i = 0; i < 4; ++i) {
        float v = acc[m][n][i] + bv_;
        C[(size_t)(row + i) * H3_ + col] = f2bf(v);
      }
    }
  }
}

// ---------------- cooperative GRU scan v8: barrier-free register flow ----------------
// 256 WGs x 512 thr, wg = b*16+s. Thread (w,g16,l16): dim jj=4w+g16 (gate lane
// l16==0), k-slice [32*l16,+32) = slots [16*l16,+16) of its batch.
// hst slot = tag32 | bf16(dim 2k) | bf16(dim 2k+1)<<16; 256 slots/batch/parity.
// Step t: poll 16 slots for tag (tbase+t) with done-mask (selective retry),
// matvec off packed bf16, 4-hop shuffle reduce, gates fp32 on l16==0, publish
// tag (tbase+t+1) at parity (tag&1). NO __syncthreads in the loop — tag-poll
// dependency both synchronizes and makes depth-2 parity overrun-safe (a wave
// reaches publish t+3 only after ALL waves published t+2, which required them
// to have consumed t+1). Weights: bf16-pair uints in w_lds[12][512] (uint4
// lane-consecutive -> conflict-free aligned b128), reloaded each step (issued
// before the poll; completes under the spin).
__global__ __launch_bounds__(512, 1)
void k_gru(const float* __restrict__ Whh_l, const float* __restrict__ bhh_l,
           const u16* __restrict__ xg, const u16* __restrict__ mixbf,
           float* __restrict__ out_h, u64* hst, int tbase) {
  const int tid = threadIdx.x;
  const int wg = blockIdx.x;
  const int b = wg >> 4, s = wg & 15;
  const int w = tid >> 6, lane = tid & 63;
  const int g16 = lane >> 4, l16 = lane & 15;
  const int jj = 4 * w + g16;
  const int d_own = s * 32 + jj;
  const bool gl = (l16 == 0);

  __shared__ u32x4 w_lds[12][512];   // 96 KiB

  // ---- startup: pack 3 rows x 32 k fp32 -> 48 bf16-pair uints -> LDS ----
  {
    unsigned wu[48];
#pragma unroll
    for (int r3 = 0; r3 < 3; ++r3) {
      const float4* src = (const float4*)(Whh_l + ((size_t)(r3 * H_ + d_own)) * H_ + l16 * 32);
#pragma unroll
      for (int c = 0; c < 8; ++c) {
        float4 f = src[c];
        wu[r3 * 16 + c * 2 + 0] = (unsigned)f2bf(f.x) | ((unsigned)f2bf(f.y) << 16);
        wu[r3 * 16 + c * 2 + 1] = (unsigned)f2bf(f.z) | ((unsigned)f2bf(f.w) << 16);
      }
    }
#pragma unroll
    for (int c = 0; c < 12; ++c) {
      u32x4 q = { wu[c * 4], wu[c * 4 + 1], wu[c * 4 + 2], wu[c * 4 + 3] };
      w_lds[c][tid] = q;
    }
  }
  const float br_ = bhh_l[0 * H_ + d_own];
  const float bz_ = bhh_l[1 * H_ + d_own];
  const float bn_ = bhh_l[2 * H_ + d_own];
  __syncthreads();   // w_lds ready; the ONLY barrier

  const u16* xgp = xg + (size_t)b * L_ * H3_ + d_own;
  const u16* mxp = mixbf + (size_t)b * L_ * H_ + d_own;
  float* outp = out_h + (size_t)b * L_ * H_ + d_own;

  float hp = 0.f;
  u16 xr_c = 0, xz_c = 0, xn_c = 0, mx_c = 0;
  if (gl) {
    xr_c = xgp[0]; xz_c = xgp[H_]; xn_c = xgp[2 * H_]; mx_c = mxp[0];
  }

  for (int t = 0; t < L_; ++t) {
    const unsigned Tc = (unsigned)(tbase + t);       // consume tag
    const unsigned Tp = Tc + 1;                      // publish tag

    // prefetch next step's gate inputs (latency = one full step)
    u16 xr_n = 0, xz_n = 0, xn_n = 0, mx_n = 0;
    if (gl && t + 1 < L_) {
      const u16* xq = xgp + (size_t)(t + 1) * H3_;
      xr_n = xq[0]; xz_n = xq[H_]; xn_n = xq[2 * H_];
      mx_n = mxp[(size_t)(t + 1) * H_];
    }

    float q0 = 0.f, q1 = 0.f, q2 = 0.f;
    if (t > 0) {
      // issue weight reloads first: ds_reads drain while we spin on vm loads
      u32x4 wq[12];
#pragma unroll
      for (int c = 0; c < 12; ++c) wq[c] = w_lds[c][tid];

      // ---- poll own 16 slots with per-slot done-mask ----
      const u64* sp = hst + (size_t)(Tc & 1) * 4096 + (size_t)b * 256 + l16 * 16;
      u64 v[16];
      unsigned mask = 0;
      do {
#pragma unroll
        for (int j = 0; j < 16; ++j)
          if (!(mask & (1u << j)))
            v[j] = __hip_atomic_load(sp + j, __ATOMIC_RELAXED, __HIP_MEMORY_SCOPE_AGENT);
#pragma unroll
        for (int j = 0; j < 16; ++j)
          if (!(mask & (1u << j)) && (unsigned)(v[j] >> 32) == Tc)
            mask |= 1u << j;
      } while (mask != 0xFFFFu);

      // ---- matvec: 3 rows x 32 k, bf16 x bf16 via shift/mask FMA ----
#pragma unroll
      for (int j = 0; j < 16; ++j) {
        const unsigned lo = (unsigned)v[j];
        const float alo = __uint_as_float(lo << 16);
        const float ahi = __uint_as_float(lo & 0xffff0000u);
        const unsigned w0 = wq[j >> 2][j & 3];
        const unsigned w1 = wq[(16 + j) >> 2][(16 + j) & 3];
        const unsigned w2 = wq[(32 + j) >> 2][(32 + j) & 3];
        q0 += __uint_as_float(w0 << 16) * alo + __uint_as_float(w0 & 0xffff0000u) * ahi;
        q1 += __uint_as_float(w1 << 16) * alo + __uint_as_float(w1 & 0xffff0000u) * ahi;
        q2 += __uint_as_float(w2 << 16) * alo + __uint_as_float(w2 & 0xffff0000u) * ahi;
      }
    }

    // reduce over 16 k-slices
    q0 += __shfl_xor(q0, 1); q1 += __shfl_xor(q1, 1); q2 += __shfl_xor(q2, 1);
    q0 += __shfl_xor(q0, 2); q1 += __shfl_xor(q1, 2); q2 += __shfl_xor(q2, 2);
    q0 += __shfl_xor(q0, 4); q1 += __shfl_xor(q1, 4); q2 += __shfl_xor(q2, 4);
    q0 += __shfl_xor(q0, 8); q1 += __shfl_xor(q1, 8); q2 += __shfl_xor(q2, 8);

    if (gl) {
      float r = fast_sig(bf2f(xr_c) + q0 + br_);
      float z = fast_sig(bf2f(xz_c) + q1 + bz_);
      float n = fast_tanh(bf2f(xn_c) + r * (q2 + bn_));
      float hnew = n + z * (hp - n);
      hp = hnew;
      unsigned myraw = (unsigned)f2bf(hnew);
      unsigned peer  = (unsigned)__shfl((int)myraw, (lane + 16) & 63);
      if ((g16 & 1) == 0) {    // publish dims (d_own, d_own+1)
        u64 pv = ((u64)Tp << 32) | (u64)(myraw | (peer << 16));
        __hip_atomic_store(hst + (size_t)(Tp & 1) * 4096 + (size_t)b * 256 + (d_own >> 1),
                           pv, __ATOMIC_RELAXED, __HIP_MEMORY_SCOPE_AGENT);
      }
      outp[(size_t)t * H_] = bf2f(mx_c) + hnew;
    }

    xr_c = xr_n; xz_c = xz_n; xn_c = xn_n; mx_c = mx_n;
  }
}

extern "C" void kernel_launch(void* const* d_in, const int* in_sizes, int n_in,
                              void* d_out, int out_size, void* d_ws, size_t ws_size,
                              hipStream_t stream) {
  (void)in_sizes; (void)n_in; (void)out_size; (void)ws_size;
  const float* x    = (const float*)d_in[0];
  const float* Wp   = (const float*)d_in[1];
  const float* bp   = (const float*)d_in[2];
  const float* ln_g = (const float*)d_in[3];
  const float* ln_b = (const float*)d_in[4];
  const float* cw0  = (const float*)d_in[5];
  const float* cb0  = (const float*)d_in[6];
  const float* cw1  = (const float*)d_in[7];
  const float* cb1  = (const float*)d_in[8];
  const float* cw2  = (const float*)d_in[9];
  const float* cb2  = (const float*)d_in[10];
  const float* bng  = (const float*)d_in[11];
  const float* bnb  = (const float*)d_in[12];
  const float* gW   = (const float*)d_in[13];
  const float* gb   = (const float*)d_in[14];
  const float* Wih  = (const float*)d_in[15];
  const float* Whh  = (const float*)d_in[16];
  const float* bih  = (const float*)d_in[17];
  const float* bhh  = (const float*)d_in[18];

  char* ws = (char*)d_ws;
  u16*   xg    = (u16*)(ws + 0);
  float* ln    = (float*)(ws + 0);  // alias: consumed (by k_mix) before k_gemm writes xg
  u16*   mixbf = (u16*)(ws + (size_t)96 * 1024 * 1024);
  u16*   wihbf = (u16*)(ws + (size_t)128 * 1024 * 1024);
  u64*   hst   = (u64*)(ws + (size_t)134 * 1024 * 1024);
  float* hbuf  = (float*)d_out;     // inter-layer h lives in d_out

  k_init<<<dim3(32), dim3(256), 0, stream>>>(hst, 8192);
  k_cvt<<<dim3(3072), dim3(256), 0, stream>>>(Wih, wihbf, NL_ * H3_ * H_);
  k_proj<<<dim3(B_ * L_ / 8), dim3(512), 0, stream>>>(x, Wp, bp, hbuf);

  for (int l = 0; l < NL_; ++l) {
    k_ln<<<dim3(B_ * L_ / 4), dim3(256), 0, stream>>>(hbuf, ln_g + l * H_, ln_b + l * H_, ln);
    k_mix<<<dim3(B_ * L_), dim3(512), 0, stream>>>(ln,
        cw0 + l * H_ * 5,  cb0 + l * H_,
        cw1 + l * H_ * 11, cb1 + l * H_,
        cw2 + l * H_ * 23, cb2 + l * H_,
        bng + l * 3 * H_, bnb + l * 3 * H_,
        gW + l * 3 * H3_, gb + l * 3, mixbf);
    k_gemm<<<dim3((B_ * L_ / 128) * (H3_ / 128)), dim3(256), 0, stream>>>(
        mixbf, wihbf + (size_t)l * H3_ * H_, bih + l * H3_, xg);

    const float* whh_l = Whh + (size_t)l * H3_ * H_;
    const float* bhh_l = bhh + l * H3_;
    const u16* xg_c = xg;
    const u16* mix_c = mixbf;
    float* outp = hbuf;
    int tbase = l * L_;
    void* args[] = { (void*)&whh_l, (void*)&bhh_l, (void*)&xg_c, (void*)&mix_c,
                     (void*)&outp, (void*)&hst, (void*)&tbase };
    hipLaunchCooperativeKernel((void*)k_gru, dim3(B_ * 16), dim3(512), args, 0, stream);
  }
}

// Round 9
// 38409.277 us; speedup vs baseline: 1.8664x; 1.8664x over previous
//
#include <hip/hip_runtime.h>
#include <hip/hip_bf16.h>

// xLSTMStack: proj -> 4x( LN -> conv-mix -> bf16 MFMA GEMM (xg) -> cooperative GRU scan + residual )
// GRU v9 = round-6 structure + two validated fixes:
//  (a) w_lds stride 104 -> 106 u16 (53 dwords, odd -> conflict-free ds_read_b128)
//  (b) packed comm: u64 slot = tag32 | bf16(d) | bf16(d+1); 256 slots/batch/parity;
//      16 publish stores + 240 independent per-slot pollers per WG (exit-on-match,
//      the round-6-proven stable pattern; NO line-gated retry, NO barrier-free flow).
// Everything else identical to round 6 (best stable: 4.51 ms/dispatch).
// Workspace (~134.1 MiB):
//   [0,96M)    xg bf16 [B*L*3H] (first 64 MiB aliased as ln fp32)
//   [96,128M)  mixbf bf16 [B*L*H]
//   [128,134M) wihbf bf16 [4*3H*H]
//   [134M,+64K) hst u64 [2][16][256]
// d_out (fp32 [B,L,H]) doubles as the inter-layer h buffer.

#define B_   16
#define L_   2048
#define IN_  64
#define H_   512
#define H3_  1536
#define NL_  4

typedef unsigned short u16;
typedef unsigned long long u64;
typedef short bf16x8 __attribute__((ext_vector_type(8)));
typedef float f32x4 __attribute__((ext_vector_type(4)));

__device__ __forceinline__ u16 f2bf(float f) {
  unsigned u = __float_as_uint(f);
  u = u + 0x7fffu + ((u >> 16) & 1u);
  return (u16)(u >> 16);
}
__device__ __forceinline__ float bf2f(u16 v) {
  return __uint_as_float(((unsigned)v) << 16);
}
__device__ __forceinline__ float gelu_exact(float x) {
  return 0.5f * x * (1.f + erff(x * 0.70710678118654752440f));
}
__device__ __forceinline__ float fast_sig(float x) {
  float e = __expf(-x);
  return __builtin_amdgcn_rcpf(1.f + e);
}
__device__ __forceinline__ float fast_tanh(float x) {
  x = fminf(fmaxf(x, -15.f), 15.f);
  float e = __expf(2.f * x);
  return (e - 1.f) * __builtin_amdgcn_rcpf(e + 1.f);
}
// 8 bf16 (packed in uint4, k-ascending) dot 8 fp32
__device__ __forceinline__ float dotw(uint4 wp, float4 ha, float4 hc) {
  float acc;
  acc  = __uint_as_float(wp.x << 16)          * ha.x;
  acc += __uint_as_float(wp.x & 0xffff0000u)  * ha.y;
  acc += __uint_as_float(wp.y << 16)          * ha.z;
  acc += __uint_as_float(wp.y & 0xffff0000u)  * ha.w;
  acc += __uint_as_float(wp.z << 16)          * hc.x;
  acc += __uint_as_float(wp.z & 0xffff0000u)  * hc.y;
  acc += __uint_as_float(wp.w << 16)          * hc.z;
  acc += __uint_as_float(wp.w & 0xffff0000u)  * hc.w;
  return acc;
}

// ---------------- init: zero tagged h-state ----------------
__global__ void k_init(u64* hst, int n) {
  int i = blockIdx.x * blockDim.x + threadIdx.x;
  if (i < n) hst[i] = 0ull;
}

// ---------------- fp32 -> bf16 convert ----------------
__global__ void k_cvt(const float* __restrict__ in, u16* __restrict__ out, int n) {
  int i = blockIdx.x * blockDim.x + threadIdx.x;
  int stride = gridDim.x * blockDim.x;
  for (; i < n; i += stride) out[i] = f2bf(in[i]);
}

// ---------------- input projection: h = x @ Wp.T + bp ----------------
__global__ __launch_bounds__(512)
void k_proj(const float* __restrict__ x, const float* __restrict__ Wp,
            const float* __restrict__ bp, float* __restrict__ hb) {
  __shared__ float4 xs[128];
  const int tid = threadIdx.x;
  const size_t m0 = (size_t)blockIdx.x * 8;
  if (tid < 128) xs[tid] = ((const float4*)(x + m0 * IN_))[tid];
  __syncthreads();
  float4 wv[16];
  const float4* wp4 = (const float4*)(Wp + (size_t)tid * IN_);
#pragma unroll
  for (int i = 0; i < 16; ++i) wv[i] = wp4[i];
  float acc[8] = {0.f,0.f,0.f,0.f,0.f,0.f,0.f,0.f};
#pragma unroll
  for (int k = 0; k < 16; ++k) {
    float4 w4 = wv[k];
#pragma unroll
    for (int rr = 0; rr < 8; ++rr) {
      float4 xv = xs[rr * 16 + k];
      acc[rr] += w4.x * xv.x + w4.y * xv.y + w4.z * xv.z + w4.w * xv.w;
    }
  }
  float bpv = bp[tid];
#pragma unroll
  for (int rr = 0; rr < 8; ++rr) hb[(m0 + rr) * H_ + tid] = acc[rr] + bpv;
}

// ---------------- LayerNorm (one wave per row) ----------------
__global__ __launch_bounds__(256)
void k_ln(const float* __restrict__ hin, const float* __restrict__ g,
          const float* __restrict__ bta, float* __restrict__ lnout) {
  const int w = threadIdx.x >> 6, lane = threadIdx.x & 63;
  const size_t m = (size_t)blockIdx.x * 4 + w;
  const float4* src = (const float4*)(hin + m * H_);
  float4 a = src[lane * 2], c = src[lane * 2 + 1];
  float sm = a.x + a.y + a.z + a.w + c.x + c.y + c.z + c.w;
  float sq = a.x*a.x + a.y*a.y + a.z*a.z + a.w*a.w + c.x*c.x + c.y*c.y + c.z*c.z + c.w*c.w;
  sm += __shfl_xor(sm, 1);  sq += __shfl_xor(sq, 1);
  sm += __shfl_xor(sm, 2);  sq += __shfl_xor(sq, 2);
  sm += __shfl_xor(sm, 4);  sq += __shfl_xor(sq, 4);
  sm += __shfl_xor(sm, 8);  sq += __shfl_xor(sq, 8);
  sm += __shfl_xor(sm, 16); sq += __shfl_xor(sq, 16);
  sm += __shfl_xor(sm, 32); sq += __shfl_xor(sq, 32);
  float mu = sm * (1.f / 512.f);
  float var = sq * (1.f / 512.f) - mu * mu;
  float inv = 1.f / sqrtf(var + 1e-5f);
  const float4* g4 = (const float4*)g;
  const float4* b4 = (const float4*)bta;
  float4 ga = g4[lane * 2], gc = g4[lane * 2 + 1];
  float4 ba = b4[lane * 2], bc = b4[lane * 2 + 1];
  float4 oa, oc;
  oa.x = (a.x - mu) * inv * ga.x + ba.x;
  oa.y = (a.y - mu) * inv * ga.y + ba.y;
  oa.z = (a.z - mu) * inv * ga.z + ba.z;
  oa.w = (a.w - mu) * inv * ga.w + ba.w;
  oc.x = (c.x - mu) * inv * gc.x + bc.x;
  oc.y = (c.y - mu) * inv * gc.y + bc.y;
  oc.z = (c.z - mu) * inv * gc.z + bc.z;
  oc.w = (c.w - mu) * inv * gc.w + bc.w;
  float4* dst = (float4*)(lnout + m * H_);
  dst[lane * 2] = oa;
  dst[lane * 2 + 1] = oc;
}

// ---------------- fused conv(5,11,23)+BN+GELU+gate softmax+mix ----------------
__global__ __launch_bounds__(512)
void k_mix(const float* __restrict__ ln,
           const float* __restrict__ w0, const float* __restrict__ cb0,
           const float* __restrict__ w1, const float* __restrict__ cb1,
           const float* __restrict__ w2, const float* __restrict__ cb2,
           const float* __restrict__ bng, const float* __restrict__ bnb,
           const float* __restrict__ gW, const float* __restrict__ gb,
           u16* __restrict__ mixbf) {
  const int h = threadIdx.x;
  const int bi = blockIdx.x >> 11;
  const int t = blockIdx.x & (L_ - 1);
  const size_t mrow = (size_t)blockIdx.x;
  float v[23];
#pragma unroll
  for (int d = 0; d < 23; ++d) {
    int tt = t + d - 11;
    v[d] = (tt >= 0 && tt < L_) ? ln[((size_t)bi * L_ + tt) * H_ + h] : 0.f;
  }
  float o0 = cb0[h], o1 = cb1[h], o2 = cb2[h];
#pragma unroll
  for (int d = 0; d < 5; ++d) o0 += v[9 + d] * w0[h * 5 + d];
#pragma unroll
  for (int d = 0; d < 11; ++d) o1 += v[6 + d] * w1[h * 11 + d];
#pragma unroll
  for (int d = 0; d < 23; ++d) o2 += v[d] * w2[h * 23 + d];
  const float bscale = 0.99999500003749968f;  // 1/sqrt(1+1e-5)
  o0 = o0 * (bng[0 * H_ + h] * bscale) + bnb[0 * H_ + h];
  o1 = o1 * (bng[1 * H_ + h] * bscale) + bnb[1 * H_ + h];
  o2 = o2 * (bng[2 * H_ + h] * bscale) + bnb[2 * H_ + h];
  o0 = gelu_exact(o0); o1 = gelu_exact(o1); o2 = gelu_exact(o2);
  float l0 = o0 * gW[0 * H3_ + h] + o1 * gW[0 * H3_ + H_ + h] + o2 * gW[0 * H3_ + 2 * H_ + h];
  float l1 = o0 * gW[1 * H3_ + h] + o1 * gW[1 * H3_ + H_ + h] + o2 * gW[1 * H3_ + 2 * H_ + h];
  float l2 = o0 * gW[2 * H3_ + h] + o1 * gW[2 * H3_ + H_ + h] + o2 * gW[2 * H3_ + 2 * H_ + h];
  l0 += __shfl_xor(l0, 1);  l1 += __shfl_xor(l1, 1);  l2 += __shfl_xor(l2, 1);
  l0 += __shfl_xor(l0, 2);  l1 += __shfl_xor(l1, 2);  l2 += __shfl_xor(l2, 2);
  l0 += __shfl_xor(l0, 4);  l1 += __shfl_xor(l1, 4);  l2 += __shfl_xor(l2, 4);
  l0 += __shfl_xor(l0, 8);  l1 += __shfl_xor(l1, 8);  l2 += __shfl_xor(l2, 8);
  l0 += __shfl_xor(l0, 16); l1 += __shfl_xor(l1, 16); l2 += __shfl_xor(l2, 16);
  l0 += __shfl_xor(l0, 32); l1 += __shfl_xor(l1, 32); l2 += __shfl_xor(l2, 32);
  __shared__ float red[8][3];
  const int w = h >> 6, lane = h & 63;
  if (lane == 0) { red[w][0] = l0; red[w][1] = l1; red[w][2] = l2; }
  __syncthreads();
  l0 = gb[0]; l1 = gb[1]; l2 = gb[2];
#pragma unroll
  for (int i = 0; i < 8; ++i) { l0 += red[i][0]; l1 += red[i][1]; l2 += red[i][2]; }
  float mx = fmaxf(l0, fmaxf(l1, l2));
  float e0 = expf(l0 - mx), e1 = expf(l1 - mx), e2 = expf(l2 - mx);
  float inv = 1.f / (e0 + e1 + e2);
  float out = (o0 * e0 + o1 * e1 + o2 * e2) * inv;
  mixbf[mrow * H_ + h] = f2bf(out);
}

// ---------------- bf16 MFMA GEMM: xg = mixbf @ WihT + bih ----------------
__global__ __launch_bounds__(256)
void k_gemm(const u16* __restrict__ A, const u16* __restrict__ Bm,
            const float* __restrict__ bias, u16* __restrict__ C) {
  __shared__ u16 As[128 * 32];
  __shared__ u16 Bs[128 * 32];
  const int tid = threadIdx.x;
  const int bm = blockIdx.x / 12, bn = blockIdx.x % 12;
  const int m0 = bm * 128, n0 = bn * 128;
  const int w = tid >> 6, lane = tid & 63;
  const int wr = w >> 1, wc = w & 1;
  const int q = lane >> 4, r = lane & 15;
  f32x4 acc[4][4] = {};
  const uint4* Ag = (const uint4*)(A + (size_t)m0 * H_);
  const uint4* Bg = (const uint4*)(Bm + (size_t)n0 * H_);
  uint4* As4 = (uint4*)As;
  uint4* Bs4 = (uint4*)Bs;
  for (int ko = 0; ko < 16; ++ko) {
    __syncthreads();
#pragma unroll
    for (int i = 0; i < 2; ++i) {
      int j = tid + 256 * i;
      As4[j] = Ag[(size_t)(j >> 2) * 64 + (j & 3) + ko * 4];
      Bs4[j] = Bg[(size_t)(j >> 2) * 64 + (j & 3) + ko * 4];
    }
    __syncthreads();
    bf16x8 av[4], bv[4];
#pragma unroll
    for (int m = 0; m < 4; ++m) av[m] = *(const bf16x8*)&As[(wr * 64 + m * 16 + r) * 32 + q * 8];
#pragma unroll
    for (int n = 0; n < 4; ++n) bv[n] = *(const bf16x8*)&Bs[(wc * 64 + n * 16 + r) * 32 + q * 8];
#pragma unroll
    for (int m = 0; m < 4; ++m)
#pragma unroll
      for (int n = 0; n < 4; ++n)
        acc[m][n] = __builtin_amdgcn_mfma_f32_16x16x32_bf16(av[m], bv[n], acc[m][n], 0, 0, 0);
  }
#pragma unroll
  for (int n = 0; n < 4; ++n) {
    int col = n0 + wc * 64 + n * 16 + r;
    float bv_ = bias[col];
#pragma unroll
    for (int m = 0; m < 4; ++m) {
      int row = m0 + wr * 64 + m * 16 + q * 4;
#pragma unroll
      for (int i = 0; i < 4; ++i) {
        float v = acc[m][n][i] + bv_;
        C[(size_t)(row + i) * H3_ + col] = f2bf(v);
      }
    }
  }
}

// ---------------- cooperative GRU scan v9 ----------------
// 256 WGs x 512 thr, wg = b*16+s. WG owns dims [32s,32s+32) = 96 gate rows.
// Thread (w,g16,l16): dim jj=4w+g16, rows {jj,512+jj,1024+jj}, k-slice
// [32*l16,+32). Weights bf16 in w_lds[512][106] (53-dword stride: conflict-free
// ds_read_b128); reloaded each step (anti-spill, drains under poll window).
// Comm: slot = tag32 | bf16(d) | bf16(d+1)<<16, 256/batch/parity; 16 publish
// stores/WG (even-g16 gate lanes, peer via shuffle); 240 pollers (tid<240),
// ONE slot each, independent exit-on-match spin (round-6-proven stable).
// Own slice written fp32 straight to LDS. One __syncthreads per step.
__global__ __launch_bounds__(512, 1)
void k_gru(const float* __restrict__ Whh_l, const float* __restrict__ bhh_l,
           const u16* __restrict__ xg, const u16* __restrict__ mixbf,
           float* __restrict__ out_h, u64* hst, int tbase) {
  const int tid = threadIdx.x;
  const int wg = blockIdx.x;
  const int b = wg >> 4, s = wg & 15;
  const int w = tid >> 6, lane = tid & 63;
  const int g16 = lane >> 4, l16 = lane & 15;
  const int jj = 4 * w + g16;
  const int d_own = s * 32 + jj;
  const bool gl = (l16 == 0);

  __shared__ __align__(16) u16 w_lds[512][106];   // 106 KiB, 53-dword stride
  __shared__ __align__(16) float h_lds[2][576];   // 4.5 KiB, skewed (36/slice)

  // ---- startup: pack this thread's 3x32 weight slice into LDS (bf16) ----
  {
    const float* s0 = Whh_l + ((size_t)0 * H_ + d_own) * H_ + l16 * 32;
    const float* s1 = Whh_l + ((size_t)1 * H_ + d_own) * H_ + l16 * 32;
    const float* s2 = Whh_l + ((size_t)2 * H_ + d_own) * H_ + l16 * 32;
#pragma unroll
    for (int c = 0; c < 4; ++c) {
      float4 a, v; u16* dst;
      a = *(const float4*)(s0 + c * 8); v = *(const float4*)(s0 + c * 8 + 4);
      dst = &w_lds[tid][c * 24 + 0];
      dst[0]=f2bf(a.x); dst[1]=f2bf(a.y); dst[2]=f2bf(a.z); dst[3]=f2bf(a.w);
      dst[4]=f2bf(v.x); dst[5]=f2bf(v.y); dst[6]=f2bf(v.z); dst[7]=f2bf(v.w);
      a = *(const float4*)(s1 + c * 8); v = *(const float4*)(s1 + c * 8 + 4);
      dst = &w_lds[tid][c * 24 + 8];
      dst[0]=f2bf(a.x); dst[1]=f2bf(a.y); dst[2]=f2bf(a.z); dst[3]=f2bf(a.w);
      dst[4]=f2bf(v.x); dst[5]=f2bf(v.y); dst[6]=f2bf(v.z); dst[7]=f2bf(v.w);
      a = *(const float4*)(s2 + c * 8); v = *(const float4*)(s2 + c * 8 + 4);
      dst = &w_lds[tid][c * 24 + 16];
      dst[0]=f2bf(a.x); dst[1]=f2bf(a.y); dst[2]=f2bf(a.z); dst[3]=f2bf(a.w);
      dst[4]=f2bf(v.x); dst[5]=f2bf(v.y); dst[6]=f2bf(v.z); dst[7]=f2bf(v.w);
    }
  }
  const float br_ = bhh_l[0 * H_ + d_own];
  const float bz_ = bhh_l[1 * H_ + d_own];
  const float bn_ = bhh_l[2 * H_ + d_own];

  h_lds[0][(tid >> 5) * 36 + (tid & 31)] = 0.f;  // h_{-1} = 0
  float hp = 0.f;
  __syncthreads();

  const u16* xgp = xg + (size_t)b * L_ * H3_ + d_own;
  const u16* mxp = mixbf + (size_t)b * L_ * H_ + d_own;
  float* outp = out_h + (size_t)b * L_ * H_ + d_own;
  const char* wbase = (const char*)&w_lds[tid][0];

  // poller mapping: tid<240 -> remote slot sigma (skips own slice's 16 slots)
  const int sigma = tid + ((tid >= s * 16) ? 16 : 0);
  const bool poller = (tid < 240);

  // prologue: weight regs + t=0 gate inputs
  uint4 wv[4][3];
#pragma unroll
  for (int c = 0; c < 4; ++c) {
    const int cp = (c + g16) & 3;
    wv[c][0] = *(const uint4*)(wbase + cp * 48);
    wv[c][1] = *(const uint4*)(wbase + cp * 48 + 16);
    wv[c][2] = *(const uint4*)(wbase + cp * 48 + 32);
  }
  u16 xr_c = 0, xz_c = 0, xn_c = 0, mx_c = 0;
  if (gl) {
    xr_c = xgp[0]; xz_c = xgp[H_]; xn_c = xgp[2 * H_]; mx_c = mxp[0];
  }

  for (int t = 0; t < L_; ++t) {
    const int cur = t & 1, nxt = cur ^ 1;
    const unsigned T = (unsigned)(tbase + t + 1);

    // prefetch next step's gate inputs
    u16 xr_n = 0, xz_n = 0, xn_n = 0, mx_n = 0;
    if (gl && t + 1 < L_) {
      const u16* xq = xgp + (size_t)(t + 1) * H3_;
      xr_n = xq[0]; xz_n = xq[H_]; xn_n = xq[2 * H_];
      mx_n = mxp[(size_t)(t + 1) * H_];
    }

    // ---- matvec: 3 rows x 32 k, weights in regs, h from skewed LDS ----
    const float* hb = &h_lds[cur][l16 * 36];
    float q0 = 0.f, q1 = 0.f, q2 = 0.f;
#pragma unroll
    for (int c = 0; c < 4; ++c) {
      const int cp = (c + g16) & 3;
      float4 ha = *(const float4*)(hb + cp * 8);
      float4 hc = *(const float4*)(hb + cp * 8 + 4);
      q0 += dotw(wv[c][0], ha, hc);
      q1 += dotw(wv[c][1], ha, hc);
      q2 += dotw(wv[c][2], ha, hc);
    }

    // reload weight regs (conflict-free; keeps allocator from spilling)
#pragma unroll
    for (int c = 0; c < 4; ++c) {
      const int cp = (c + g16) & 3;
      wv[c][0] = *(const uint4*)(wbase + cp * 48);
      wv[c][1] = *(const uint4*)(wbase + cp * 48 + 16);
      wv[c][2] = *(const uint4*)(wbase + cp * 48 + 32);
    }

    // reduce over 16 k-slices
    q0 += __shfl_xor(q0, 1); q1 += __shfl_xor(q1, 1); q2 += __shfl_xor(q2, 1);
    q0 += __shfl_xor(q0, 2); q1 += __shfl_xor(q1, 2); q2 += __shfl_xor(q2, 2);
    q0 += __shfl_xor(q0, 4); q1 += __shfl_xor(q1, 4); q2 += __shfl_xor(q2, 4);
    q0 += __shfl_xor(q0, 8); q1 += __shfl_xor(q1, 8); q2 += __shfl_xor(q2, 8);

    if (gl) {
      float r = fast_sig(bf2f(xr_c) + q0 + br_);
      float z = fast_sig(bf2f(xz_c) + q1 + bz_);
      float n = fast_tanh(bf2f(xn_c) + r * (q2 + bn_));
      float hnew = n + z * (hp - n);
      hp = hnew;
      unsigned myraw = (unsigned)f2bf(hnew);
      unsigned peer  = (unsigned)__shfl((int)myraw, (lane + 16) & 63);
      if (t + 1 < L_) {
        if ((g16 & 1) == 0) {   // publish dims (d_own, d_own+1) as one packed slot
          u64 pv = ((u64)T << 32) | (u64)(myraw | (peer << 16));
          __hip_atomic_store(hst + (size_t)nxt * 4096 + (size_t)b * 256 + (d_own >> 1),
                             pv, __ATOMIC_RELAXED, __HIP_MEMORY_SCOPE_AGENT);
        }
        h_lds[nxt][s * 36 + jj] = hnew;  // own dim: exact fp32 straight to LDS
      }
      outp[(size_t)t * H_] = bf2f(mx_c) + hnew;
    }

    // ---- poll: one remote slot per poller thread, exit on tag match ----
    if (poller && t + 1 < L_) {
      const u64* sl = hst + (size_t)nxt * 4096 + (size_t)b * 256 + sigma;
      u64 v;
      do {
        v = __hip_atomic_load(sl, __ATOMIC_RELAXED, __HIP_MEMORY_SCOPE_AGENT);
      } while ((unsigned)(v >> 32) != T);
      float* hd = &h_lds[nxt][(sigma >> 4) * 36 + 2 * (sigma & 15)];
      hd[0] = bf2f((u16)v);
      hd[1] = bf2f((u16)(v >> 16));
    }
    __syncthreads();

    xr_c = xr_n; xz_c = xz_n; xn_c = xn_n; mx_c = mx_n;
  }
}

extern "C" void kernel_launch(void* const* d_in, const int* in_sizes, int n_in,
                              void* d_out, int out_size, void* d_ws, size_t ws_size,
                              hipStream_t stream) {
  (void)in_sizes; (void)n_in; (void)out_size; (void)ws_size;
  const float* x    = (const float*)d_in[0];
  const float* Wp   = (const float*)d_in[1];
  const float* bp   = (const float*)d_in[2];
  const float* ln_g = (const float*)d_in[3];
  const float* ln_b = (const float*)d_in[4];
  const float* cw0  = (const float*)d_in[5];
  const float* cb0  = (const float*)d_in[6];
  const float* cw1  = (const float*)d_in[7];
  const float* cb1  = (const float*)d_in[8];
  const float* cw2  = (const float*)d_in[9];
  const float* cb2  = (const float*)d_in[10];
  const float* bng  = (const float*)d_in[11];
  const float* bnb  = (const float*)d_in[12];
  const float* gW   = (const float*)d_in[13];
  const float* gb   = (const float*)d_in[14];
  const float* Wih  = (const float*)d_in[15];
  const float* Whh  = (const float*)d_in[16];
  const float* bih  = (const float*)d_in[17];
  const float* bhh  = (const float*)d_in[18];

  char* ws = (char*)d_ws;
  u16*   xg    = (u16*)(ws + 0);
  float* ln    = (float*)(ws + 0);  // alias: consumed (by k_mix) before k_gemm writes xg
  u16*   mixbf = (u16*)(ws + (size_t)96 * 1024 * 1024);
  u16*   wihbf = (u16*)(ws + (size_t)128 * 1024 * 1024);
  u64*   hst   = (u64*)(ws + (size_t)134 * 1024 * 1024);
  float* hbuf  = (float*)d_out;     // inter-layer h lives in d_out

  k_init<<<dim3(32), dim3(256), 0, stream>>>(hst, 8192);
  k_cvt<<<dim3(3072), dim3(256), 0, stream>>>(Wih, wihbf, NL_ * H3_ * H_);
  k_proj<<<dim3(B_ * L_ / 8), dim3(512), 0, stream>>>(x, Wp, bp, hbuf);

  for (int l = 0; l < NL_; ++l) {
    k_ln<<<dim3(B_ * L_ / 4), dim3(256), 0, stream>>>(hbuf, ln_g + l * H_, ln_b + l * H_, ln);
    k_mix<<<dim3(B_ * L_), dim3(512), 0, stream>>>(ln,
        cw0 + l * H_ * 5,  cb0 + l * H_,
        cw1 + l * H_ * 11, cb1 + l * H_,
        cw2 + l * H_ * 23, cb2 + l * H_,
        bng + l * 3 * H_, bnb + l * 3 * H_,
        gW + l * 3 * H3_, gb + l * 3, mixbf);
    k_gemm<<<dim3((B_ * L_ / 128) * (H3_ / 128)), dim3(256), 0, stream>>>(
        mixbf, wihbf + (size_t)l * H3_ * H_, bih + l * H3_, xg);

    const float* whh_l = Whh + (size_t)l * H3_ * H_;
    const float* bhh_l = bhh + l * H3_;
    const u16* xg_c = xg;
    const u16* mix_c = mixbf;
    float* outp = hbuf;
    int tbase = l * L_;
    void* args[] = { (void*)&whh_l, (void*)&bhh_l, (void*)&xg_c, (void*)&mix_c,
                     (void*)&outp, (void*)&hst, (void*)&tbase };
    hipLaunchCooperativeKernel((void*)k_gru, dim3(B_ * 16), dim3(512), args, 0, stream);
  }
}

// Round 10
// 17356.696 us; speedup vs baseline: 4.1302x; 2.2129x over previous
//
#include <hip/hip_runtime.h>
#include <hip/hip_bf16.h>

// xLSTMStack: proj -> 4x( LN -> conv-mix -> bf16 MFMA GEMM (xg) -> cooperative GRU scan + residual )
// GRU v10 = round-6 structure EXACTLY (best stable: 4.51 ms/dispatch), with ONE
// change: weight LDS layout [512][104] u16 -> [12][512] uint4 planes indexed
// [chunk][tid] (round-8-measured ZERO bank conflicts; lanes hit consecutive
// 16B slots). Same bf16-pair packing, same per-step wv reload (anti-spill),
// same comm fabric (fp32 u64 slots, 32 publishes, 480 one-slot pollers, one
// __syncthreads per step) — comm changes destabilized rounds 7/8/9; untouched.
// Workspace (~134.2 MiB):
//   [0,96M)    xg bf16 [B*L*3H] (first 64 MiB aliased as ln fp32)
//   [96,128M)  mixbf bf16 [B*L*H]
//   [128,134M) wihbf bf16 [4*3H*H]
//   [134M,+128K) hst u64 [2][16][512]
// d_out (fp32 [B,L,H]) doubles as the inter-layer h buffer.

#define B_   16
#define L_   2048
#define IN_  64
#define H_   512
#define H3_  1536
#define NL_  4

typedef unsigned short u16;
typedef unsigned long long u64;
typedef short bf16x8 __attribute__((ext_vector_type(8)));
typedef float f32x4 __attribute__((ext_vector_type(4)));
typedef unsigned u32x4 __attribute__((ext_vector_type(4)));

__device__ __forceinline__ u16 f2bf(float f) {
  unsigned u = __float_as_uint(f);
  u = u + 0x7fffu + ((u >> 16) & 1u);
  return (u16)(u >> 16);
}
__device__ __forceinline__ float bf2f(u16 v) {
  return __uint_as_float(((unsigned)v) << 16);
}
__device__ __forceinline__ float gelu_exact(float x) {
  return 0.5f * x * (1.f + erff(x * 0.70710678118654752440f));
}
__device__ __forceinline__ float fast_sig(float x) {
  float e = __expf(-x);
  return __builtin_amdgcn_rcpf(1.f + e);
}
__device__ __forceinline__ float fast_tanh(float x) {
  x = fminf(fmaxf(x, -15.f), 15.f);
  float e = __expf(2.f * x);
  return (e - 1.f) * __builtin_amdgcn_rcpf(e + 1.f);
}
// 8 bf16 (packed in u32x4, k-ascending) dot 8 fp32
__device__ __forceinline__ float dotw(u32x4 wp, float4 ha, float4 hc) {
  float acc;
  acc  = __uint_as_float(wp.x << 16)          * ha.x;
  acc += __uint_as_float(wp.x & 0xffff0000u)  * ha.y;
  acc += __uint_as_float(wp.y << 16)          * ha.z;
  acc += __uint_as_float(wp.y & 0xffff0000u)  * ha.w;
  acc += __uint_as_float(wp.z << 16)          * hc.x;
  acc += __uint_as_float(wp.z & 0xffff0000u)  * hc.y;
  acc += __uint_as_float(wp.w << 16)          * hc.z;
  acc += __uint_as_float(wp.w & 0xffff0000u)  * hc.w;
  return acc;
}

// ---------------- init: zero tagged h-state ----------------
__global__ void k_init(u64* hst, int n) {
  int i = blockIdx.x * blockDim.x + threadIdx.x;
  if (i < n) hst[i] = 0ull;
}

// ---------------- fp32 -> bf16 convert ----------------
__global__ void k_cvt(const float* __restrict__ in, u16* __restrict__ out, int n) {
  int i = blockIdx.x * blockDim.x + threadIdx.x;
  int stride = gridDim.x * blockDim.x;
  for (; i < n; i += stride) out[i] = f2bf(in[i]);
}

// ---------------- input projection: h = x @ Wp.T + bp ----------------
__global__ __launch_bounds__(512)
void k_proj(const float* __restrict__ x, const float* __restrict__ Wp,
            const float* __restrict__ bp, float* __restrict__ hb) {
  __shared__ float4 xs[128];
  const int tid = threadIdx.x;
  const size_t m0 = (size_t)blockIdx.x * 8;
  if (tid < 128) xs[tid] = ((const float4*)(x + m0 * IN_))[tid];
  __syncthreads();
  float4 wv[16];
  const float4* wp4 = (const float4*)(Wp + (size_t)tid * IN_);
#pragma unroll
  for (int i = 0; i < 16; ++i) wv[i] = wp4[i];
  float acc[8] = {0.f,0.f,0.f,0.f,0.f,0.f,0.f,0.f};
#pragma unroll
  for (int k = 0; k < 16; ++k) {
    float4 w4 = wv[k];
#pragma unroll
    for (int rr = 0; rr < 8; ++rr) {
      float4 xv = xs[rr * 16 + k];
      acc[rr] += w4.x * xv.x + w4.y * xv.y + w4.z * xv.z + w4.w * xv.w;
    }
  }
  float bpv = bp[tid];
#pragma unroll
  for (int rr = 0; rr < 8; ++rr) hb[(m0 + rr) * H_ + tid] = acc[rr] + bpv;
}

// ---------------- LayerNorm (one wave per row) ----------------
__global__ __launch_bounds__(256)
void k_ln(const float* __restrict__ hin, const float* __restrict__ g,
          const float* __restrict__ bta, float* __restrict__ lnout) {
  const int w = threadIdx.x >> 6, lane = threadIdx.x & 63;
  const size_t m = (size_t)blockIdx.x * 4 + w;
  const float4* src = (const float4*)(hin + m * H_);
  float4 a = src[lane * 2], c = src[lane * 2 + 1];
  float sm = a.x + a.y + a.z + a.w + c.x + c.y + c.z + c.w;
  float sq = a.x*a.x + a.y*a.y + a.z*a.z + a.w*a.w + c.x*c.x + c.y*c.y + c.z*c.z + c.w*c.w;
  sm += __shfl_xor(sm, 1);  sq += __shfl_xor(sq, 1);
  sm += __shfl_xor(sm, 2);  sq += __shfl_xor(sq, 2);
  sm += __shfl_xor(sm, 4);  sq += __shfl_xor(sq, 4);
  sm += __shfl_xor(sm, 8);  sq += __shfl_xor(sq, 8);
  sm += __shfl_xor(sm, 16); sq += __shfl_xor(sq, 16);
  sm += __shfl_xor(sm, 32); sq += __shfl_xor(sq, 32);
  float mu = sm * (1.f / 512.f);
  float var = sq * (1.f / 512.f) - mu * mu;
  float inv = 1.f / sqrtf(var + 1e-5f);
  const float4* g4 = (const float4*)g;
  const float4* b4 = (const float4*)bta;
  float4 ga = g4[lane * 2], gc = g4[lane * 2 + 1];
  float4 ba = b4[lane * 2], bc = b4[lane * 2 + 1];
  float4 oa, oc;
  oa.x = (a.x - mu) * inv * ga.x + ba.x;
  oa.y = (a.y - mu) * inv * ga.y + ba.y;
  oa.z = (a.z - mu) * inv * ga.z + ba.z;
  oa.w = (a.w - mu) * inv * ga.w + ba.w;
  oc.x = (c.x - mu) * inv * gc.x + bc.x;
  oc.y = (c.y - mu) * inv * gc.y + bc.y;
  oc.z = (c.z - mu) * inv * gc.z + bc.z;
  oc.w = (c.w - mu) * inv * gc.w + bc.w;
  float4* dst = (float4*)(lnout + m * H_);
  dst[lane * 2] = oa;
  dst[lane * 2 + 1] = oc;
}

// ---------------- fused conv(5,11,23)+BN+GELU+gate softmax+mix ----------------
__global__ __launch_bounds__(512)
void k_mix(const float* __restrict__ ln,
           const float* __restrict__ w0, const float* __restrict__ cb0,
           const float* __restrict__ w1, const float* __restrict__ cb1,
           const float* __restrict__ w2, const float* __restrict__ cb2,
           const float* __restrict__ bng, const float* __restrict__ bnb,
           const float* __restrict__ gW, const float* __restrict__ gb,
           u16* __restrict__ mixbf) {
  const int h = threadIdx.x;
  const int bi = blockIdx.x >> 11;
  const int t = blockIdx.x & (L_ - 1);
  const size_t mrow = (size_t)blockIdx.x;
  float v[23];
#pragma unroll
  for (int d = 0; d < 23; ++d) {
    int tt = t + d - 11;
    v[d] = (tt >= 0 && tt < L_) ? ln[((size_t)bi * L_ + tt) * H_ + h] : 0.f;
  }
  float o0 = cb0[h], o1 = cb1[h], o2 = cb2[h];
#pragma unroll
  for (int d = 0; d < 5; ++d) o0 += v[9 + d] * w0[h * 5 + d];
#pragma unroll
  for (int d = 0; d < 11; ++d) o1 += v[6 + d] * w1[h * 11 + d];
#pragma unroll
  for (int d = 0; d < 23; ++d) o2 += v[d] * w2[h * 23 + d];
  const float bscale = 0.99999500003749968f;  // 1/sqrt(1+1e-5)
  o0 = o0 * (bng[0 * H_ + h] * bscale) + bnb[0 * H_ + h];
  o1 = o1 * (bng[1 * H_ + h] * bscale) + bnb[1 * H_ + h];
  o2 = o2 * (bng[2 * H_ + h] * bscale) + bnb[2 * H_ + h];
  o0 = gelu_exact(o0); o1 = gelu_exact(o1); o2 = gelu_exact(o2);
  float l0 = o0 * gW[0 * H3_ + h] + o1 * gW[0 * H3_ + H_ + h] + o2 * gW[0 * H3_ + 2 * H_ + h];
  float l1 = o0 * gW[1 * H3_ + h] + o1 * gW[1 * H3_ + H_ + h] + o2 * gW[1 * H3_ + 2 * H_ + h];
  float l2 = o0 * gW[2 * H3_ + h] + o1 * gW[2 * H3_ + H_ + h] + o2 * gW[2 * H3_ + 2 * H_ + h];
  l0 += __shfl_xor(l0, 1);  l1 += __shfl_xor(l1, 1);  l2 += __shfl_xor(l2, 1);
  l0 += __shfl_xor(l0, 2);  l1 += __shfl_xor(l1, 2);  l2 += __shfl_xor(l2, 2);
  l0 += __shfl_xor(l0, 4);  l1 += __shfl_xor(l1, 4);  l2 += __shfl_xor(l2, 4);
  l0 += __shfl_xor(l0, 8);  l1 += __shfl_xor(l1, 8);  l2 += __shfl_xor(l2, 8);
  l0 += __shfl_xor(l0, 16); l1 += __shfl_xor(l1, 16); l2 += __shfl_xor(l2, 16);
  l0 += __shfl_xor(l0, 32); l1 += __shfl_xor(l1, 32); l2 += __shfl_xor(l2, 32);
  __shared__ float red[8][3];
  const int w = h >> 6, lane = h & 63;
  if (lane == 0) { red[w][0] = l0; red[w][1] = l1; red[w][2] = l2; }
  __syncthreads();
  l0 = gb[0]; l1 = gb[1]; l2 = gb[2];
#pragma unroll
  for (int i = 0; i < 8; ++i) { l0 += red[i][0]; l1 += red[i][1]; l2 += red[i][2]; }
  float mx = fmaxf(l0, fmaxf(l1, l2));
  float e0 = expf(l0 - mx), e1 = expf(l1 - mx), e2 = expf(l2 - mx);
  float inv = 1.f / (e0 + e1 + e2);
  float out = (o0 * e0 + o1 * e1 + o2 * e2) * inv;
  mixbf[mrow * H_ + h] = f2bf(out);
}

// ---------------- bf16 MFMA GEMM: xg = mixbf @ WihT + bih ----------------
__global__ __launch_bounds__(256)
void k_gemm(const u16* __restrict__ A, const u16* __restrict__ Bm,
            const float* __restrict__ bias, u16* __restrict__ C) {
  __shared__ u16 As[128 * 32];
  __shared__ u16 Bs[128 * 32];
  const int tid = threadIdx.x;
  const int bm = blockIdx.x / 12, bn = blockIdx.x % 12;
  const int m0 = bm * 128, n0 = bn * 128;
  const int w = tid >> 6, lane = tid & 63;
  const int wr = w >> 1, wc = w & 1;
  const int q = lane >> 4, r = lane & 15;
  f32x4 acc[4][4] = {};
  const uint4* Ag = (const uint4*)(A + (size_t)m0 * H_);
  const uint4* Bg = (const uint4*)(Bm + (size_t)n0 * H_);
  uint4* As4 = (uint4*)As;
  uint4* Bs4 = (uint4*)Bs;
  for (int ko = 0; ko < 16; ++ko) {
    __syncthreads();
#pragma unroll
    for (int i = 0; i < 2; ++i) {
      int j = tid + 256 * i;
      As4[j] = Ag[(size_t)(j >> 2) * 64 + (j & 3) + ko * 4];
      Bs4[j] = Bg[(size_t)(j >> 2) * 64 + (j & 3) + ko * 4];
    }
    __syncthreads();
    bf16x8 av[4], bv[4];
#pragma unroll
    for (int m = 0; m < 4; ++m) av[m] = *(const bf16x8*)&As[(wr * 64 + m * 16 + r) * 32 + q * 8];
#pragma unroll
    for (int n = 0; n < 4; ++n) bv[n] = *(const bf16x8*)&Bs[(wc * 64 + n * 16 + r) * 32 + q * 8];
#pragma unroll
    for (int m = 0; m < 4; ++m)
#pragma unroll
      for (int n = 0; n < 4; ++n)
        acc[m][n] = __builtin_amdgcn_mfma_f32_16x16x32_bf16(av[m], bv[n], acc[m][n], 0, 0, 0);
  }
#pragma unroll
  for (int n = 0; n < 4; ++n) {
    int col = n0 + wc * 64 + n * 16 + r;
    float bv_ = bias[col];
#pragma unroll
    for (int m = 0; m < 4; ++m) {
      int row = m0 + wr * 64 + m * 16 + q * 4;
#pragma unroll
      for (int i = 0; i < 4; ++i) {
        float v = acc[m][n][i] + bv_;
        C[(size_t)(row + i) * H3_ + col] = f2bf(v);
      }
    }
  }
}

// ---------------- cooperative GRU scan v10 ----------------
// 256 WGs x 512 thr, wg = b*16+s. WG owns dims [32s,32s+32) = 96 gate rows.
// Thread (w,g16,l16): dim jj=4w+g16, rows {jj,512+jj,1024+jj}, k-slice
// [32*l16,+32). Weights: bf16-pair u32x4 planes w_lds[12][512], indexed
// [row*4+chunk][tid] — lanes read consecutive 16B slots: ZERO bank conflicts
// (round-8-measured). wv[4][3] reloaded each step (anti-spill; drains under
// the publish/poll window). Comm identical to round 6: slot/dim fp32-tagged
// u64, 32 publishes (gate lanes), 480 one-slot exit-on-match pollers, own
// slice straight to LDS, one __syncthreads per step.
__global__ __launch_bounds__(512, 1)
void k_gru(const float* __restrict__ Whh_l, const float* __restrict__ bhh_l,
           const u16* __restrict__ xg, const u16* __restrict__ mixbf,
           float* __restrict__ out_h, u64* hst, int tbase) {
  const int tid = threadIdx.x;
  const int wg = blockIdx.x;
  const int b = wg >> 4, s = wg & 15;
  const int w = tid >> 6, lane = tid & 63;
  const int g16 = lane >> 4, l16 = lane & 15;
  const int jj = 4 * w + g16;
  const int d_own = s * 32 + jj;
  const bool gl = (l16 == 0);

  __shared__ u32x4 w_lds[12][512];                // 96 KiB, conflict-free planes
  __shared__ __align__(16) float h_lds[2][576];   // 4.5 KiB, skewed (36/slice)

  // ---- startup: pack 3 rows x 32 k fp32 -> bf16 pairs -> plane layout ----
  {
    unsigned wu[48];
#pragma unroll
    for (int r3 = 0; r3 < 3; ++r3) {
      const float4* src = (const float4*)(Whh_l + ((size_t)(r3 * H_ + d_own)) * H_ + l16 * 32);
#pragma unroll
      for (int c = 0; c < 8; ++c) {
        float4 f = src[c];
        wu[r3 * 16 + c * 2 + 0] = (unsigned)f2bf(f.x) | ((unsigned)f2bf(f.y) << 16);
        wu[r3 * 16 + c * 2 + 1] = (unsigned)f2bf(f.z) | ((unsigned)f2bf(f.w) << 16);
      }
    }
#pragma unroll
    for (int c = 0; c < 12; ++c) {
      u32x4 q = { wu[c * 4], wu[c * 4 + 1], wu[c * 4 + 2], wu[c * 4 + 3] };
      w_lds[c][tid] = q;   // plane c = (row c/4, k-chunk c%4): k in [ (c%4)*8, +8 )
    }
  }
  const float br_ = bhh_l[0 * H_ + d_own];
  const float bz_ = bhh_l[1 * H_ + d_own];
  const float bn_ = bhh_l[2 * H_ + d_own];

  h_lds[0][(tid >> 5) * 36 + (tid & 31)] = 0.f;  // h_{-1} = 0
  float hp = 0.f;
  __syncthreads();

  const u16* xgp = xg + (size_t)b * L_ * H3_ + d_own;
  const u16* mxp = mixbf + (size_t)b * L_ * H_ + d_own;
  float* outp = out_h + (size_t)b * L_ * H_ + d_own;

  // prologue: weight regs (chunk rotation matches h-read rotation) + t=0 inputs
  u32x4 wv[4][3];
#pragma unroll
  for (int c = 0; c < 4; ++c) {
    const int cp = (c + g16) & 3;
    wv[c][0] = w_lds[0 * 4 + cp][tid];
    wv[c][1] = w_lds[1 * 4 + cp][tid];
    wv[c][2] = w_lds[2 * 4 + cp][tid];
  }
  u16 xr_c = 0, xz_c = 0, xn_c = 0, mx_c = 0;
  if (gl) {
    xr_c = xgp[0]; xz_c = xgp[H_]; xn_c = xgp[2 * H_]; mx_c = mxp[0];
  }

  for (int t = 0; t < L_; ++t) {
    const int cur = t & 1, nxt = cur ^ 1;
    const unsigned T = (unsigned)(tbase + t + 1);

    // prefetch next step's gate inputs
    u16 xr_n = 0, xz_n = 0, xn_n = 0, mx_n = 0;
    if (gl && t + 1 < L_) {
      const u16* xq = xgp + (size_t)(t + 1) * H3_;
      xr_n = xq[0]; xz_n = xq[H_]; xn_n = xq[2 * H_];
      mx_n = mxp[(size_t)(t + 1) * H_];
    }

    // ---- matvec: 3 rows x 32 k, weights in regs, h from skewed LDS ----
    const float* hb = &h_lds[cur][l16 * 36];
    float q0 = 0.f, q1 = 0.f, q2 = 0.f;
#pragma unroll
    for (int c = 0; c < 4; ++c) {
      const int cp = (c + g16) & 3;
      float4 ha = *(const float4*)(hb + cp * 8);
      float4 hc = *(const float4*)(hb + cp * 8 + 4);
      q0 += dotw(wv[c][0], ha, hc);
      q1 += dotw(wv[c][1], ha, hc);
      q2 += dotw(wv[c][2], ha, hc);
    }

    // reload weight regs (conflict-free planes; keeps allocator from spilling)
#pragma unroll
    for (int c = 0; c < 4; ++c) {
      const int cp = (c + g16) & 3;
      wv[c][0] = w_lds[0 * 4 + cp][tid];
      wv[c][1] = w_lds[1 * 4 + cp][tid];
      wv[c][2] = w_lds[2 * 4 + cp][tid];
    }

    // reduce over 16 k-slices
    q0 += __shfl_xor(q0, 1); q1 += __shfl_xor(q1, 1); q2 += __shfl_xor(q2, 1);
    q0 += __shfl_xor(q0, 2); q1 += __shfl_xor(q1, 2); q2 += __shfl_xor(q2, 2);
    q0 += __shfl_xor(q0, 4); q1 += __shfl_xor(q1, 4); q2 += __shfl_xor(q2, 4);
    q0 += __shfl_xor(q0, 8); q1 += __shfl_xor(q1, 8); q2 += __shfl_xor(q2, 8);

    if (gl) {
      float r = fast_sig(bf2f(xr_c) + q0 + br_);
      float z = fast_sig(bf2f(xz_c) + q1 + bz_);
      float n = fast_tanh(bf2f(xn_c) + r * (q2 + bn_));
      float hnew = n + z * (hp - n);
      hp = hnew;
      if (t + 1 < L_) {  // publish first: it's on the other WGs' critical path
        __hip_atomic_store(&hst[(size_t)nxt * 8192 + (b << 9) + d_own],
                           ((u64)T << 32) | (u64)__float_as_uint(hnew),
                           __ATOMIC_RELAXED, __HIP_MEMORY_SCOPE_AGENT);
        h_lds[nxt][s * 36 + jj] = hnew;   // own dim straight to LDS
      }
      outp[(size_t)t * H_] = bf2f(mx_c) + hnew;
    }

    // ---- poll: thread tid owns dim tid of own batch ----
    if (t + 1 < L_ && (tid >> 5) != s) {
      u64* sl = &hst[(size_t)nxt * 8192 + (b << 9) + tid];
      u64 v;
      do {
        v = __hip_atomic_load(sl, __ATOMIC_RELAXED, __HIP_MEMORY_SCOPE_AGENT);
      } while ((unsigned)(v >> 32) != T);
      h_lds[nxt][(tid >> 5) * 36 + (tid & 31)] = __uint_as_float((unsigned)v);
    }
    __syncthreads();

    xr_c = xr_n; xz_c = xz_n; xn_c = xn_n; mx_c = mx_n;
  }
}

extern "C" void kernel_launch(void* const* d_in, const int* in_sizes, int n_in,
                              void* d_out, int out_size, void* d_ws, size_t ws_size,
                              hipStream_t stream) {
  (void)in_sizes; (void)n_in; (void)out_size; (void)ws_size;
  const float* x    = (const float*)d_in[0];
  const float* Wp   = (const float*)d_in[1];
  const float* bp   = (const float*)d_in[2];
  const float* ln_g = (const float*)d_in[3];
  const float* ln_b = (const float*)d_in[4];
  const float* cw0  = (const float*)d_in[5];
  const float* cb0  = (const float*)d_in[6];
  const float* cw1  = (const float*)d_in[7];
  const float* cb1  = (const float*)d_in[8];
  const float* cw2  = (const float*)d_in[9];
  const float* cb2  = (const float*)d_in[10];
  const float* bng  = (const float*)d_in[11];
  const float* bnb  = (const float*)d_in[12];
  const float* gW   = (const float*)d_in[13];
  const float* gb   = (const float*)d_in[14];
  const float* Wih  = (const float*)d_in[15];
  const float* Whh  = (const float*)d_in[16];
  const float* bih  = (const float*)d_in[17];
  const float* bhh  = (const float*)d_in[18];

  char* ws = (char*)d_ws;
  u16*   xg    = (u16*)(ws + 0);
  float* ln    = (float*)(ws + 0);  // alias: consumed (by k_mix) before k_gemm writes xg
  u16*   mixbf = (u16*)(ws + (size_t)96 * 1024 * 1024);
  u16*   wihbf = (u16*)(ws + (size_t)128 * 1024 * 1024);
  u64*   hst   = (u64*)(ws + (size_t)134 * 1024 * 1024);
  float* hbuf  = (float*)d_out;     // inter-layer h lives in d_out

  k_init<<<dim3(64), dim3(256), 0, stream>>>(hst, 2 * B_ * H_);
  k_cvt<<<dim3(3072), dim3(256), 0, stream>>>(Wih, wihbf, NL_ * H3_ * H_);
  k_proj<<<dim3(B_ * L_ / 8), dim3(512), 0, stream>>>(x, Wp, bp, hbuf);

  for (int l = 0; l < NL_; ++l) {
    k_ln<<<dim3(B_ * L_ / 4), dim3(256), 0, stream>>>(hbuf, ln_g + l * H_, ln_b + l * H_, ln);
    k_mix<<<dim3(B_ * L_), dim3(512), 0, stream>>>(ln,
        cw0 + l * H_ * 5,  cb0 + l * H_,
        cw1 + l * H_ * 11, cb1 + l * H_,
        cw2 + l * H_ * 23, cb2 + l * H_,
        bng + l * 3 * H_, bnb + l * 3 * H_,
        gW + l * 3 * H3_, gb + l * 3, mixbf);
    k_gemm<<<dim3((B_ * L_ / 128) * (H3_ / 128)), dim3(256), 0, stream>>>(
        mixbf, wihbf + (size_t)l * H3_ * H_, bih + l * H3_, xg);

    const float* whh_l = Whh + (size_t)l * H3_ * H_;
    const float* bhh_l = bhh + l * H3_;
    const u16* xg_c = xg;
    const u16* mix_c = mixbf;
    float* outp = hbuf;
    int tbase = l * L_;
    void* args[] = { (void*)&whh_l, (void*)&bhh_l, (void*)&xg_c, (void*)&mix_c,
                     (void*)&outp, (void*)&hst, (void*)&tbase };
    hipLaunchCooperativeKernel((void*)k_gru, dim3(B_ * 16), dim3(512), args, 0, stream);
  }
}